// Round 1
// baseline (337.702 us; speedup 1.0000x reference)
//
#include <hip/hip_runtime.h>
#include <math.h>

#define N_TOK 2000
#define NH 8
#define HD 32
#define SCALE 25.0f
#define SIM_TH 0.75f
#define EPSF 1e-8f
#define NSLOT 8   // ceil(2000/256)
#define NTAIL 208 // valid lanes in slot 7: 2000 - 7*256
#define SPAD 2048 // padded score-plane stride

typedef _Float16 half2_t __attribute__((ext_vector_type(2)));

__device__ __forceinline__ unsigned rflu(unsigned u) {
  return (unsigned)__builtin_amdgcn_readfirstlane((int)u);
}
__device__ __forceinline__ half2_t u2h(unsigned u) {
  return __builtin_bit_cast(half2_t, u);
}
__device__ __forceinline__ unsigned h2u(half2_t h) {
  return __builtin_bit_cast(unsigned, h);
}

// f32 += f16x2 . f16x2 (v_dot2_f32_f16; products exact, fp32 accumulate)
__device__ __forceinline__ float fdot2f(unsigned a, unsigned b, float c) {
#if __has_builtin(__builtin_amdgcn_fdot2)
  return __builtin_amdgcn_fdot2(u2h(a), u2h(b), c, false);
#else
  const half2_t ha = u2h(a), hb = u2h(b);
  return c + (float)ha.x * (float)hb.x + (float)ha.y * (float)hb.y;
#endif
}

// packed block reductions over 256 threads (4 waves); red must hold 4*NV
template <int NV>
__device__ __forceinline__ void block_sumN(float* v, float* red) {
#pragma unroll
  for (int off = 32; off > 0; off >>= 1) {
#pragma unroll
    for (int q = 0; q < NV; q++) v[q] += __shfl_xor(v[q], off, 64);
  }
  __syncthreads();
  const int wid = threadIdx.x >> 6;
  if ((threadIdx.x & 63) == 0) {
#pragma unroll
    for (int q = 0; q < NV; q++) red[wid * NV + q] = v[q];
  }
  __syncthreads();
#pragma unroll
  for (int q = 0; q < NV; q++) {
    v[q] = (red[q] + red[NV + q]) + (red[2 * NV + q] + red[3 * NV + q]);
  }
}
template <int NV>
__device__ __forceinline__ void block_maxN(float* v, float* red) {
#pragma unroll
  for (int off = 32; off > 0; off >>= 1) {
#pragma unroll
    for (int q = 0; q < NV; q++) v[q] = fmaxf(v[q], __shfl_xor(v[q], off, 64));
  }
  __syncthreads();
  const int wid = threadIdx.x >> 6;
  if ((threadIdx.x & 63) == 0) {
#pragma unroll
    for (int q = 0; q < NV; q++) red[wid * NV + q] = v[q];
  }
  __syncthreads();
#pragma unroll
  for (int q = 0; q < NV; q++) {
    v[q] = fmaxf(fmaxf(red[q], red[NV + q]),
                 fmaxf(red[2 * NV + q], red[3 * NV + q]));
  }
}

// load 4 query rows' packed-f16 data. qp0/qp1 -> SGPR (rflu); qp2/qp3 stay
// in VGPR on purpose: SGPR file can't hold 64 uniform words, and at 2
// blocks/CU (LDS-bound) the per-wave VGPR budget is 256 -> free.
#define LOAD_Q4(BUF)                                                      \
  {                                                                       \
    const uint4* __restrict__ qb =                                        \
        (const uint4*)(BUF) + (size_t)h * 4 * N_TOK;                      \
    _Pragma("unroll") for (int gg = 0; gg < 4; gg++) {                    \
      const uint4 a0 = qb[gg * N_TOK + i0];                               \
      const uint4 a1 = qb[gg * N_TOK + i1];                               \
      const uint4 a2 = qb[gg * N_TOK + i2];                               \
      const uint4 a3 = qb[gg * N_TOK + i3];                               \
      qp0[4 * gg + 0] = rflu(a0.x); qp0[4 * gg + 1] = rflu(a0.y);         \
      qp0[4 * gg + 2] = rflu(a0.z); qp0[4 * gg + 3] = rflu(a0.w);         \
      qp1[4 * gg + 0] = rflu(a1.x); qp1[4 * gg + 1] = rflu(a1.y);         \
      qp1[4 * gg + 2] = rflu(a1.z); qp1[4 * gg + 3] = rflu(a1.w);         \
      qp2[4 * gg + 0] = a2.x; qp2[4 * gg + 1] = a2.y;                     \
      qp2[4 * gg + 2] = a2.z; qp2[4 * gg + 3] = a2.w;                     \
      qp3[4 * gg + 0] = a3.x; qp3[4 * gg + 1] = a3.y;                     \
      qp3[4 * gg + 2] = a3.z; qp3[4 * gg + 3] = a3.w;                     \
    }                                                                     \
  }

#define DOT4(KW, QP, D)                                                   \
  D = fdot2f((KW).x, QP[4 * g_ + 0], D);                                  \
  D = fdot2f((KW).y, QP[4 * g_ + 1], D);                                  \
  D = fdot2f((KW).z, QP[4 * g_ + 2], D);                                  \
  D = fdot2f((KW).w, QP[4 * g_ + 3], D);

// ---------------------------------------------------------------------------
// Kernel 0: pack W fp32 [256][768] into f16 pair-quads Wq[k/8][768].
// grid = (96, 2), block = 256
// ---------------------------------------------------------------------------
__global__ __launch_bounds__(256) void wpack_kernel(
    const float* __restrict__ W_cls, const float* __restrict__ W_reg,
    unsigned* __restrict__ Wp_cls, unsigned* __restrict__ Wp_reg) {
  const int idx = blockIdx.x * 256 + threadIdx.x;
  const int kq = idx / 768, c = idx % 768;
  const float* __restrict__ W = blockIdx.y ? W_reg : W_cls;
  uint4* __restrict__ Wq = (uint4*)(blockIdx.y ? Wp_reg : Wp_cls);
  uint4 o;
  o.x = h2u((half2_t){(_Float16)W[(8 * kq + 0) * 768 + c],
                      (_Float16)W[(8 * kq + 1) * 768 + c]});
  o.y = h2u((half2_t){(_Float16)W[(8 * kq + 2) * 768 + c],
                      (_Float16)W[(8 * kq + 3) * 768 + c]});
  o.z = h2u((half2_t){(_Float16)W[(8 * kq + 4) * 768 + c],
                      (_Float16)W[(8 * kq + 5) * 768 + c]});
  o.w = h2u((half2_t){(_Float16)W[(8 * kq + 6) * 768 + c],
                      (_Float16)W[(8 * kq + 7) * 768 + c]});
  Wq[idx] = o;
}

// ---------------------------------------------------------------------------
// Kernel 1: QKV projection via f16 W + fdot2, 4 rows/block (measured best).
// grid = (500, 2), block = 256
// ---------------------------------------------------------------------------
__global__ __launch_bounds__(256) void qkv_norm_kernel(
    const float* __restrict__ x_cls, const float* __restrict__ x_reg,
    const unsigned* __restrict__ Wp_cls, const unsigned* __restrict__ Wp_reg,
    _Float16* __restrict__ qc_h, _Float16* __restrict__ qr_h,
    _Float16* __restrict__ kc_h, _Float16* __restrict__ kr_h,
    _Float16* __restrict__ vn_h, float* __restrict__ v_rm,
    _Float16* __restrict__ v_h) {
  __shared__ unsigned xs_p[4][128];
  __shared__ float res[4][768];
  __shared__ float inv_norm[96];

  const int n0 = blockIdx.x * 4;
  const int which = blockIdx.y;
  const int tid = threadIdx.x;
  const float* __restrict__ x = which ? x_reg : x_cls;
  const uint4* __restrict__ Wq = (const uint4*)(which ? Wp_reg : Wp_cls);

  if (tid < 128) {
#pragma unroll
    for (int r = 0; r < 4; r++) {
      const float2 xv = ((const float2*)x)[(size_t)(n0 + r) * 128 + tid];
      xs_p[r][tid] = h2u((half2_t){(_Float16)xv.x, (_Float16)xv.y});
    }
  }
  __syncthreads();

  float acc[4][3];
#pragma unroll
  for (int r = 0; r < 4; r++) acc[r][0] = acc[r][1] = acc[r][2] = 0.f;

#pragma unroll 2
  for (int kq = 0; kq < 32; kq++) {
    const uint4 w0 = Wq[kq * 768 + tid];
    const uint4 w1 = Wq[kq * 768 + tid + 256];
    const uint4 w2 = Wq[kq * 768 + tid + 512];
#pragma unroll
    for (int r = 0; r < 4; r++) {
      const uint4 xp = *(const uint4*)&xs_p[r][kq * 4];
      acc[r][0] = fdot2f(w0.x, xp.x, acc[r][0]);
      acc[r][0] = fdot2f(w0.y, xp.y, acc[r][0]);
      acc[r][0] = fdot2f(w0.z, xp.z, acc[r][0]);
      acc[r][0] = fdot2f(w0.w, xp.w, acc[r][0]);
      acc[r][1] = fdot2f(w1.x, xp.x, acc[r][1]);
      acc[r][1] = fdot2f(w1.y, xp.y, acc[r][1]);
      acc[r][1] = fdot2f(w1.z, xp.z, acc[r][1]);
      acc[r][1] = fdot2f(w1.w, xp.w, acc[r][1]);
      acc[r][2] = fdot2f(w2.x, xp.x, acc[r][2]);
      acc[r][2] = fdot2f(w2.y, xp.y, acc[r][2]);
      acc[r][2] = fdot2f(w2.z, xp.z, acc[r][2]);
      acc[r][2] = fdot2f(w2.w, xp.w, acc[r][2]);
    }
  }
#pragma unroll
  for (int r = 0; r < 4; r++) {
    res[r][tid] = acc[r][0];
    res[r][tid + 256] = acc[r][1];
    res[r][tid + 512] = acc[r][2];
  }
  __syncthreads();

  if (tid < 96) {
    const int r = tid / 24, grp = tid % 24;
    float ss = 0.f;
#pragma unroll
    for (int d = 0; d < HD; d++) {
      const float v = res[r][grp * 32 + d];
      ss += v * v;
    }
    inv_norm[tid] = 1.0f / (sqrtf(ss) + EPSF);
  }
  __syncthreads();

#pragma unroll
  for (int j = 0; j < 3; j++) {
    const int c = tid + j * 256;
    const int qkv = c >> 8, grp = c >> 5;
    const int h = grp & 7, d = c & 31;
    const int gg = d >> 3, dd = d & 7;
#pragma unroll
    for (int r = 0; r < 4; r++) {
      const int n = n0 + r;
      const float val = res[r][c];
      const float nval = val * inv_norm[r * 24 + grp];
      const size_t fi = ((size_t)(h * 4 + gg) * N_TOK + n) * 8 + dd;
      if (qkv == 0) {
        (which ? qr_h : qc_h)[fi] = (_Float16)nval;
      } else if (qkv == 1) {
        (which ? kr_h : kc_h)[fi] = (_Float16)nval;
      } else if (which == 0) {
        v_rm[(h * N_TOK + n) * HD + d] = val;
        vn_h[fi] = (_Float16)nval;
        v_h[((size_t)h * N_TOK + n) * HD + d] = (_Float16)val;
      }
    }
  }
}

// ---------------------------------------------------------------------------
// Kernel 2 (r21 -> r22): TQ=2 -> TQ=4. Theory: r13-r20 showed the kernel is
// pinned at ~29 B/cy/CU of L2/LLC streaming; traffic = (2000/TQ blocks) x
// 4 MB of K/VN/V planes. TQ=4 halves streamed bytes (4.0 -> 2.0 GB) with
// total VALU work constant. LDS grows to ~66.7 KB (2 blocks/CU = 8 waves/CU,
// >= measured ~7 today). qp0/qp1 uniform via rflu (SGPR); qp2/qp3 kept in
// VGPR (SGPR file can't hold 64 words; VGPR budget 256/wave at this occ).
// Per-row decade masks (4-row blocks straddle decade boundaries).
// grid = 500, block = 256
// ---------------------------------------------------------------------------
__global__ __launch_bounds__(256) void attn22_kernel(
    const _Float16* __restrict__ qc_h, const _Float16* __restrict__ qr_h,
    const _Float16* __restrict__ kc_h, const _Float16* __restrict__ kr_h,
    const _Float16* __restrict__ vn_h, const float* __restrict__ v_rm,
    const _Float16* __restrict__ v_h,
    float* __restrict__ out_x, float* __restrict__ out_sim) {
  __shared__ float s_attn[4][SPAD];  // 32 KB; tails stay 0 for PV
  __shared__ float s_union[8448];    // 33.8 KB: er[4][2048] / part (str 33)
  __shared__ float red[32];

  float* __restrict__ s_er = s_union;  // er plane r at r*SPAD
  float* __restrict__ part = s_union;  // [64 slices][4 g2] units of 33 floats

  const int tid = threadIdx.x;
  const int i0 = blockIdx.x * 4;
  const int i1 = i0 + 1, i2 = i0 + 2, i3 = i0 + 3;
  const int bs0 = (i0 / 10) * 10, bs1 = (i1 / 10) * 10;
  const int bs2 = (i2 / 10) * 10, bs3 = (i3 / 10) * 10;

  float sim[4][NSLOT], raw[4][NSLOT];
#pragma unroll
  for (int r = 0; r < 4; r++) {
#pragma unroll
    for (int t = 0; t < NSLOT; t++) { sim[r][t] = 0.f; raw[r][t] = 0.f; }
  }
  if (tid < SPAD - N_TOK) {
#pragma unroll
    for (int r = 0; r < 4; r++) s_attn[r][N_TOK + tid] = 0.f;
  }
  __syncthreads();

  unsigned qp0[16], qp1[16], qp2[16], qp3[16];

  // 3-stage pipelined sweep: loads for t+2 in flight during t's compute.
  auto sweep = [&](const uint4* __restrict__ kt4, auto&& emit) {
    uint4 ka[4], kb[4];
#pragma unroll
    for (int g_ = 0; g_ < 4; g_++) ka[g_] = kt4[g_ * N_TOK + tid];  // t=0
    {
      const int m1 = tid + 256;  // t=1 always valid
#pragma unroll
      for (int g_ = 0; g_ < 4; g_++) kb[g_] = kt4[g_ * N_TOK + m1];
    }
#pragma unroll
    for (int t = 0; t < NSLOT; t++) {
      uint4 kc_[4];
      if (t < NSLOT - 2) {  // prefetch t+2
        const int m2 = tid + 256 * (t + 2);
        const bool v2 = (t + 2 < 7) || (tid < NTAIL);
        const int mc2 = v2 ? m2 : (N_TOK - 1);
#pragma unroll
        for (int g_ = 0; g_ < 4; g_++) kc_[g_] = kt4[g_ * N_TOK + mc2];
      }
      float d0 = 0.f, d1 = 0.f, d2 = 0.f, d3 = 0.f;
#pragma unroll
      for (int g_ = 0; g_ < 4; g_++) {
        DOT4(ka[g_], qp0, d0);
        DOT4(ka[g_], qp1, d1);
        DOT4(ka[g_], qp2, d2);
        DOT4(ka[g_], qp3, d3);
      }
      emit(t, d0, d1, d2, d3);
#pragma unroll
      for (int g_ = 0; g_ < 4; g_++) {
        ka[g_] = kb[g_];
        kb[g_] = kc_[g_];
      }
    }
  };

  for (int hh = 0; hh < NH; hh++) {
    const int h = (blockIdx.x + hh) & 7;  // XCD-local head schedule

    float sums[8];  // cls x4, reg x4
#pragma unroll
    for (int q = 0; q < 8; q++) sums[q] = 0.f;

    // ===== phase C: cls scores -> e = exp(s-25) -> s_attn (unnormalized) ===
    LOAD_Q4(qc_h);
    sweep((const uint4*)kc_h + (size_t)h * 4 * N_TOK,
          [&](int t, float d0, float d1, float d2, float d3) {
            const int m = tid + 256 * t;
            const bool valid = (t < 7) || (tid < NTAIL);
            const float e0 = valid ? __expf(d0 * SCALE - SCALE) : 0.f;
            const float e1 = valid ? __expf(d1 * SCALE - SCALE) : 0.f;
            const float e2 = valid ? __expf(d2 * SCALE - SCALE) : 0.f;
            const float e3 = valid ? __expf(d3 * SCALE - SCALE) : 0.f;
            sums[0] += e0; sums[1] += e1; sums[2] += e2; sums[3] += e3;
            if (valid) {
              s_attn[0][m] = e0;
              s_attn[1][m] = e1;
              s_attn[2][m] = e2;
              s_attn[3][m] = e3;
            }
          });

    // ===== phase R: reg scores -> s_er — NO reduction between phases =====
    LOAD_Q4(qr_h);
    sweep((const uint4*)kr_h + (size_t)h * 4 * N_TOK,
          [&](int t, float d0, float d1, float d2, float d3) {
            const int m = tid + 256 * t;
            const bool valid = (t < 7) || (tid < NTAIL);
            const float e0 = valid ? __expf(d0 * SCALE - SCALE) : 0.f;
            const float e1 = valid ? __expf(d1 * SCALE - SCALE) : 0.f;
            const float e2 = valid ? __expf(d2 * SCALE - SCALE) : 0.f;
            const float e3 = valid ? __expf(d3 * SCALE - SCALE) : 0.f;
            sums[4] += e0; sums[5] += e1; sums[6] += e2; sums[7] += e3;
            if (valid) {
              s_er[m] = e0;
              s_er[SPAD + m] = e1;
              s_er[2 * SPAD + m] = e2;
              s_er[3 * SPAD + m] = e3;
            }
          });

    // ===== ONE packed reduction for all 8 softmax sums =====
    block_sumN<8>(sums, red);
    const float nc0 = 0.5f / sums[0], nc1 = 0.5f / sums[1];
    const float nc2 = 0.5f / sums[2], nc3 = 0.5f / sums[3];
    const float nr0 = 0.5f / sums[4], nr1 = 0.5f / sums[5];
    const float nr2 = 0.5f / sums[6], nr3 = 0.5f / sums[7];

    // ===== combine, mask (per-row decade), sim += =====
#pragma unroll
    for (int t = 0; t < NSLOT; t++) {
      const int m = tid + 256 * t;
      if ((t < 7) || (tid < NTAIL)) {
        float a0 = s_attn[0][m] * nc0 + s_er[m] * nr0;
        float a1 = s_attn[1][m] * nc1 + s_er[SPAD + m] * nr1;
        float a2 = s_attn[2][m] * nc2 + s_er[2 * SPAD + m] * nr2;
        float a3 = s_attn[3][m] * nc3 + s_er[3 * SPAD + m] * nr3;
        if (m >= bs0 && m < bs0 + 9 && m != i0) a0 = 0.f;
        if (m >= bs1 && m < bs1 + 9 && m != i1) a1 = 0.f;
        if (m >= bs2 && m < bs2 + 9 && m != i2) a2 = 0.f;
        if (m >= bs3 && m < bs3 + 9 && m != i3) a3 = 0.f;
        s_attn[0][m] = a0;
        s_attn[1][m] = a1;
        s_attn[2][m] = a2;
        s_attn[3][m] = a3;
        sim[0][t] += a0;
        sim[1][t] += a1;
        sim[2][t] += a2;
        sim[3][t] += a3;
      }
    }

    // ===== phase V: vn cosine -> raw += =====
    LOAD_Q4(vn_h);
    sweep((const uint4*)vn_h + (size_t)h * 4 * N_TOK,
          [&](int t, float d0, float d1, float d2, float d3) {
            const bool valid = (t < 7) || (tid < NTAIL);
            if (valid) {
              raw[0][t] += d0;
              raw[1][t] += d1;
              raw[2][t] += d2;
              raw[3][t] += d3;
            }
          });
    __syncthreads();  // s_attn final; s_er reads done -> part may reuse

    // ===== attn @ V : f16 V row-major, one uint4 = 8 d per load =====
    {
      const int g2 = tid & 3;      // d-group of 8
      const int slice = tid >> 2;  // 64 slices x 32 m
      const int m0 = slice * 32;
      float acc[4][8];
#pragma unroll
      for (int r = 0; r < 4; r++)
#pragma unroll
        for (int e = 0; e < 8; e++) acc[r][e] = 0.f;
      const _Float16* __restrict__ vb =
          v_h + (size_t)h * N_TOK * HD + g2 * 8;
#pragma unroll 2
      for (int jj = 0; jj < 8; jj++) {
        const int m = m0 + 4 * ((jj + slice) & 7);  // rotated: <=2-way LDS
        const float4 av0 = *(const float4*)&s_attn[0][m];
        const float4 av1 = *(const float4*)&s_attn[1][m];
        const float4 av2 = *(const float4*)&s_attn[2][m];
        const float4 av3 = *(const float4*)&s_attn[3][m];
        // m can reach 2047; av=0 there. v_h overrun (<=1.5k elems) lands in
        // the adjacent f16 plane (finite values; contribution x0 = 0).
        uint4 vv[4];
#pragma unroll
        for (int mm = 0; mm < 4; mm++) {
          vv[mm] = *(const uint4*)(vb + (size_t)(m + mm) * HD);
        }
#pragma unroll
        for (int mm = 0; mm < 4; mm++) {
          const float a0 = ((const float*)&av0)[mm];
          const float a1 = ((const float*)&av1)[mm];
          const float a2 = ((const float*)&av2)[mm];
          const float a3 = ((const float*)&av3)[mm];
          const unsigned* vp = (const unsigned*)&vv[mm];
#pragma unroll
          for (int e = 0; e < 4; e++) {
            const half2_t hv = u2h(vp[e]);
            const float vx = (float)hv.x, vy = (float)hv.y;
            acc[0][2 * e] += a0 * vx;
            acc[0][2 * e + 1] += a0 * vy;
            acc[1][2 * e] += a1 * vx;
            acc[1][2 * e + 1] += a1 * vy;
            acc[2][2 * e] += a2 * vx;
            acc[2][2 * e + 1] += a2 * vy;
            acc[3][2 * e] += a3 * vx;
            acc[3][2 * e + 1] += a3 * vy;
          }
        }
      }
      __syncthreads();  // er reads long done; part write safe
      float* pu = part + (size_t)(slice * 4 + g2) * 33;  // stride 33
#pragma unroll
      for (int r = 0; r < 4; r++)
#pragma unroll
        for (int e = 0; e < 8; e++) pu[r * 8 + e] = acc[r][e];
    }
    __syncthreads();
    if (tid < 128) {
      const int q = tid >> 5, d = tid & 31;
      const int g = d >> 3, e = d & 7;
      float s = 0.f;
#pragma unroll 8
      for (int sl = 0; sl < 64; sl++) {
        s += part[(size_t)(sl * 4 + g) * 33 + q * 8 + e];
      }
      const int irow = i0 + q;
      out_x[(size_t)irow * 512 + h * 32 + d] = s;
    } else {
      const int q = (tid - 128) >> 5, d = (tid - 128) & 31;
      const int irow = i0 + q;
      out_x[(size_t)irow * 512 + 256 + h * 32 + d] =
          v_rm[((size_t)h * N_TOK + irow) * HD + d];
    }
    __syncthreads();  // part reads done -> s_er reuse next head
  }

  // ===== sim_round2 epilogue, from registers, 4 rows packed =====
  float lm[4];
#pragma unroll
  for (int r = 0; r < 4; r++) {
    lm[r] = -1e30f;
#pragma unroll
    for (int t = 0; t < NSLOT; t++) {
      if ((t < 7) || (tid < NTAIL)) lm[r] = fmaxf(lm[r], sim[r][t] * 0.125f);
    }
  }
  block_maxN<4>(lm, red);

  float ls[4];
#pragma unroll
  for (int r = 0; r < 4; r++) {
    ls[r] = 0.f;
#pragma unroll
    for (int t = 0; t < NSLOT; t++) {
      const bool valid = (t < 7) || (tid < NTAIL);
      const float e = valid ? __expf(sim[r][t] * 0.125f - lm[r]) : 0.f;
      sim[r][t] = e;
      ls[r] += e;
    }
  }
  block_sumN<4>(ls, red);

  float lms[4];
#pragma unroll
  for (int r = 0; r < 4; r++) {
    const float invS = 1.0f / ls[r];
    lms[r] = 0.f;
#pragma unroll
    for (int t = 0; t < NSLOT; t++) {
      const bool valid = (t < 7) || (tid < NTAIL);
      const float p = sim[r][t] * invS;
      const float mp = (valid && (raw[r][t] * 0.125f > SIM_TH)) ? p : 0.f;
      sim[r][t] = mp;
      lms[r] += mp;
    }
  }
  block_sumN<4>(lms, red);

#pragma unroll
  for (int r = 0; r < 4; r++) {
    const float invMS = 1.0f / (lms[r] + EPSF);
    const int irow = i0 + r;
#pragma unroll
    for (int t = 0; t < NSLOT; t++) {
      const int m = tid + 256 * t;
      if ((t < 7) || (tid < NTAIL)) {
        out_sim[(size_t)irow * N_TOK + m] = sim[r][t] * invMS;
      }
    }
  }
}

// ---------------------------------------------------------------------------
extern "C" void kernel_launch(void* const* d_in, const int* in_sizes, int n_in,
                              void* d_out, int out_size, void* d_ws,
                              size_t ws_size, hipStream_t stream) {
  const float* x_cls = (const float*)d_in[0];
  const float* x_reg = (const float*)d_in[1];
  const float* W_cls = (const float*)d_in[2];
  const float* W_reg = (const float*)d_in[3];

  // ws layout: v_rm fp32, v_h f16 (NOT last: PV overrun must hit finite f16
  // data), then the score planes, then packed W.
  const size_t seg = (size_t)NH * N_TOK * HD;  // 512000 elements
  float* v_rm = (float*)d_ws;
  _Float16* v_h = (_Float16*)(v_rm + seg);
  _Float16* qc_h = v_h + seg;
  _Float16* qr_h = qc_h + seg;
  _Float16* kc_h = qr_h + seg;
  _Float16* kr_h = kc_h + seg;
  _Float16* vn_h = kr_h + seg;
  unsigned* Wp_cls = (unsigned*)(vn_h + seg);  // 98304 uints each
  unsigned* Wp_reg = Wp_cls + 98304;

  dim3 g0(96, 2);
  wpack_kernel<<<g0, 256, 0, stream>>>(W_cls, W_reg, Wp_cls, Wp_reg);

  dim3 g1(500, 2);
  qkv_norm_kernel<<<g1, 256, 0, stream>>>(x_cls, x_reg, Wp_cls, Wp_reg, qc_h,
                                          qr_h, kc_h, kr_h, vn_h, v_rm, v_h);

  float* out_x = (float*)d_out;                  // [2000, 512]
  float* out_sim = out_x + (size_t)N_TOK * 512;  // [2000, 2000]
  attn22_kernel<<<500, 256, 0, stream>>>(qc_h, qr_h, kc_h, kr_h, vn_h, v_rm,
                                         v_h, out_x, out_sim);
}